// Round 11
// baseline (13753.873 us; speedup 1.0000x reference)
//
#include <hip/hip_runtime.h>

// ACT RNN, T=8192, IO=32, H=256, M=4, EPS=0.01. f32 in/out.
// Round 11: MFMA act_chain. Rounds 6-10 proved the allocator will not keep a
// weight tile in arch VGPRs across a barriered loop (VALU matvec pays ~2.5x
// instr bloat, 12.1 ms floor). Fix: weights as bf16 MFMA A-frags -- if the
// allocator parks them in AGPRs, MFMA reads AGPRs natively (parking = free).
// 4 waves x 64 rows, 32x mfma_f32_16x16x32_bf16 per iter (B = s broadcast
// over 16 cols; wasted cols are free FLOPs). Matvec runs speculatively across
// the halt: by linearity Ws·h = sum_n w_n*y_n, so the halt-step MFMA output
// IS next timestep's step-0 preactivation (step 0 needs no matvec at all).
// tanh/halting deduped: y -> LDS, each lane owns ONE row (1 tanh, 1 fma),
// 6-DPP wave reduce -> plds[4]. Carry/acc stay f32; only matvec I/O is bf16.
// ws = 8.45 MB (acc_s aliases U in place).

#define T_  8192
#define IO_ 32
#define H_  256

typedef __attribute__((ext_vector_type(8))) __bf16 bf16x8;
typedef __attribute__((ext_vector_type(4))) float  f32x4;

__device__ __forceinline__ unsigned short f2bf(float f) {
    union { float f; unsigned int u; } v;
    v.f = f;
    unsigned int u = v.u;
    u += 0x7FFFu + ((u >> 16) & 1u);   // RNE
    return (unsigned short)(u >> 16);
}

template<int CTRL>
__device__ __forceinline__ float dpp_addf(float x) {
    int xi = __builtin_bit_cast(int, x);
    int d = __builtin_amdgcn_update_dpp(xi, xi, CTRL, 0xF, 0xF, false);
    return x + __builtin_bit_cast(float, d);
}

// full 64-lane sum -> valid in lane 63
__device__ __forceinline__ float wave_sum63(float x) {
    x = dpp_addf<0xB1>(x);    // quad_perm xor1
    x = dpp_addf<0x4E>(x);    // quad_perm xor2  (quad-uniform now)
    x = dpp_addf<0x124>(x);   // row_ror:4
    x = dpp_addf<0x128>(x);   // row_ror:8      (row-of-16 total, all lanes)
    x = dpp_addf<0x142>(x);   // row_bcast15
    x = dpp_addf<0x143>(x);   // row_bcast31 -> lane63 = wave total
    return x;
}

// ---------------- k_prep ----------------
__global__ void k_prep(const float* __restrict__ Wx,
                       const float* __restrict__ Wp,
                       const float* __restrict__ bp,
                       const float* __restrict__ b,
                       float* __restrict__ WxpT, float* __restrict__ cvec) {
    int h = blockIdx.x;
    int t = threadIdx.x;
    __shared__ float wxrow[H_];
    for (int j = t; j < H_; j += 64) wxrow[j] = Wx[h * (H_ + 1) + j];
    __syncthreads();
    if (t < IO_) {
        float acc = 0.0f;
        for (int j = 0; j < H_; ++j) acc += wxrow[j] * Wp[j * IO_ + t];
        WxpT[t * H_ + h] = acc;
    } else if (t == IO_) {
        float acc = b[h];
        for (int j = 0; j < H_; ++j) acc += wxrow[j] * bp[j];
        cvec[h] = acc;
    }
}

// ---------------- k_u ----------------
__global__ void k_u(const float* __restrict__ x,
                    const float* __restrict__ WxpT,
                    const float* __restrict__ cvec,
                    float* __restrict__ U) {
    int t0 = blockIdx.x * 8;
    int tid = threadIdx.x;
    __shared__ float xsf[8 * IO_];
    xsf[tid] = x[(size_t)t0 * IO_ + tid];
    __syncthreads();
    int h = tid;
    float base = cvec[h];
    for (int tt = 0; tt < 8; ++tt) {
        float acc = base;
        #pragma unroll
        for (int io = 0; io < IO_; ++io)
            acc += WxpT[io * H_ + h] * xsf[tt * IO_ + io];
        U[(size_t)(t0 + tt) * H_ + h] = acc;
    }
}

// ---------------- act_chain (MFMA) ----------------
__global__ __launch_bounds__(256, 1) void act_chain(
    const float* __restrict__ Ws,
    const float* __restrict__ Wx,
    const float* __restrict__ wh,
    const float* __restrict__ bh1,
    const float* __restrict__ h0,
    float* __restrict__ UAcc,
    float* __restrict__ cumArr,
    float* __restrict__ pc_out)
{
    __shared__ __align__(16) unsigned short sbuf[H_];  // s (bf16) for B-frags
    __shared__ __align__(16) float ybuf[H_];           // y = Ws·s (f32)
    __shared__ __align__(16) float plds[4];            // wave partials of wh·s

    const int tid  = threadIdx.x;      // 0..255  == owned row L
    const int w    = tid >> 6;         // wave 0..3, rows [64w, 64w+64)
    const int l    = tid & 63;
    const int quad = l >> 4;
    const int col  = l & 15;
    const int L    = tid;

    // A-frags: Ws rows 64w+16b+col, k-chunk c: 8 bf16 at [c*32+quad*8 .. +8)
    bf16x8 af[4][8];
    #pragma unroll
    for (int b = 0; b < 4; ++b) {
        const float* row = Ws + (size_t)(w * 64 + b * 16 + col) * H_;
        #pragma unroll
        for (int c = 0; c < 8; ++c) {
            union { unsigned short u[8]; bf16x8 v; } tmp;
            #pragma unroll
            for (int j = 0; j < 8; ++j)
                tmp.u[j] = f2bf(row[c * 32 + quad * 8 + j]);
            af[b][c] = tmp.v;
        }
    }

    const float wlL = Wx[(size_t)L * (H_ + 1) + H_];   // first-step flag col
    const float whL = wh[L];
    const float bhf = bh1[0];
    const float thresh = 1.0f - 0.01f;
    const float L2E  = 1.4426950408889634f;
    const float L2E2 = 2.8853900817779268f;

    // ---- prolog: Wsh = (Ws·h0)[L] ----
    sbuf[L] = f2bf(h0[L]);
    __syncthreads();
    float Wsh;
    {
        f32x4 C[4] = {{0,0,0,0},{0,0,0,0},{0,0,0,0},{0,0,0,0}};
        #pragma unroll
        for (int c = 0; c < 8; ++c) {
            bf16x8 bf = *reinterpret_cast<const bf16x8*>(
                (const char*)sbuf + c * 64 + quad * 16);
            #pragma unroll
            for (int b = 0; b < 4; ++b)
                C[b] = __builtin_amdgcn_mfma_f32_16x16x32_bf16(af[b][c], bf, C[b], 0, 0, 0);
        }
        if (col == 0) {
            #pragma unroll
            for (int b = 0; b < 4; ++b)
                *(f32x4*)(&ybuf[w * 64 + b * 16 + quad * 4]) = C[b];
        }
        __syncthreads();
        Wsh = ybuf[L];
    }

    // ---- t=0 step 0: s1 = tanh(u + flag + Ws·h) ----
    float u = UAcc[L];
    float s, pc = 0.0f;
    {
        float a = u + wlL + Wsh;
        float e = __builtin_amdgcn_exp2f(a * L2E2);
        s = __builtin_fmaf(-2.0f, __builtin_amdgcn_rcpf(e + 1.0f), 1.0f);
        float part = wave_sum63(whL * s);
        if (l == 63) plds[w] = part;
        sbuf[L] = f2bf(s);
    }
    float acc = 0.0f, Wacc = 0.0f, cum = 0.0f, nup = 1.0f;
    __syncthreads();

    #pragma unroll 1
    for (int t = 0; t < T_; ++t) {
        float un = (t + 1 < T_) ? UAcc[(size_t)(t + 1) * H_ + L] : 0.0f;

        #pragma unroll 1
        for (int k = 1; k <= 4; ++k) {
            // speculative matvec y = Ws·s_k (needed even on halt, for Wsh)
            f32x4 C[4] = {{0,0,0,0},{0,0,0,0},{0,0,0,0},{0,0,0,0}};
            #pragma unroll
            for (int c = 0; c < 8; ++c) {
                bf16x8 bf = *reinterpret_cast<const bf16x8*>(
                    (const char*)sbuf + c * 64 + quad * 16);
                #pragma unroll
                for (int b = 0; b < 4; ++b)
                    C[b] = __builtin_amdgcn_mfma_f32_16x16x32_bf16(af[b][c], bf, C[b], 0, 0, 0);
            }

            // halting decision for s_k (plds published at previous stage)
            f32x4 pv = *(const f32x4*)plds;
            float dot = (pv[0] + pv[1]) + (pv[2] + pv[3]);
            float p = __builtin_amdgcn_rcpf(
                1.0f + __builtin_amdgcn_exp2f(-(dot + bhf) * L2E));
            bool halt = (cum + p > thresh) || (k == 4);
            float hw = 1.0f - cum;
            float wn = halt ? hw : p;
            acc = __builtin_fmaf(wn, s, acc);
            cum += wn;

            if (col == 0) {
                #pragma unroll
                for (int b = 0; b < 4; ++b)
                    *(f32x4*)(&ybuf[w * 64 + b * 16 + quad * 4]) = C[b];
            }
            __syncthreads();

            float yL = ybuf[L];
            Wacc = __builtin_fmaf(wn, yL, Wacc);

            if (halt) {
                // timestep close + fused step0 of t+1
                pc = (pc + nup + hw) * (1.0f / (float)T_);
                UAcc[(size_t)t * H_ + L] = acc;       // acc_s (h) in place
                if (tid == 0) cumArr[t] = cum;
                float a = un + wlL + Wacc;            // Ws·h = Wacc (linearity)
                float e = __builtin_amdgcn_exp2f(a * L2E2);
                s = __builtin_fmaf(-2.0f, __builtin_amdgcn_rcpf(e + 1.0f), 1.0f);
                float part = wave_sum63(whL * s);
                if (l == 63) plds[w] = part;
                sbuf[L] = f2bf(s);
                u = un;
                acc = 0.0f; Wacc = 0.0f; cum = 0.0f; nup = 1.0f;
                __syncthreads();
                break;
            } else {
                float a = u + yL;                     // no flag for k>=1
                float e = __builtin_amdgcn_exp2f(a * L2E2);
                s = __builtin_fmaf(-2.0f, __builtin_amdgcn_rcpf(e + 1.0f), 1.0f);
                float part = wave_sum63(whL * s);
                if (l == 63) plds[w] = part;
                sbuf[L] = f2bf(s);
                nup += 1.0f;
                __syncthreads();
            }
        }
    }
    if (tid == 0) pc_out[0] = pc;
}

// ---------------- k_out ----------------
__global__ void k_out(const float* __restrict__ AccS,
                      const float* __restrict__ Wo,
                      const float* __restrict__ bo,
                      const float* __restrict__ cumArr,
                      float* __restrict__ ys) {
    int t0 = blockIdx.x * 8;
    int tid = threadIdx.x;   // 256
    __shared__ float wo[IO_ * 257];
    __shared__ float as[8 * 260];
    for (int i = tid; i < IO_ * H_; i += 256) {
        int o = i / H_, h = i % H_;
        wo[o * 257 + h] = Wo[i];
    }
    for (int i = tid; i < 8 * H_; i += 256) {
        int tt = i / H_, h = i % H_;
        as[tt * 260 + h] = AccS[(size_t)t0 * H_ + i];
    }
    __syncthreads();
    int tt = tid >> 5, o = tid & 31;
    float acc = cumArr[t0 + tt] * bo[o];
    #pragma unroll 4
    for (int h = 0; h < H_; ++h) acc += wo[o * 257 + h] * as[tt * 260 + h];
    ys[(size_t)(t0 + tt) * IO_ + o] = acc;
}

extern "C" void kernel_launch(void* const* d_in, const int* in_sizes, int n_in,
                              void* d_out, int out_size, void* d_ws, size_t ws_size,
                              hipStream_t stream) {
    const float* x  = (const float*)d_in[0];
    const float* h0 = (const float*)d_in[1];
    const float* Wp = (const float*)d_in[2];
    const float* bp = (const float*)d_in[3];
    const float* Wx = (const float*)d_in[4];
    const float* Ws = (const float*)d_in[5];
    const float* b  = (const float*)d_in[6];
    const float* wh = (const float*)d_in[7];
    const float* bh = (const float*)d_in[8];
    const float* Wo = (const float*)d_in[9];
    const float* bo = (const float*)d_in[10];
    float* out = (float*)d_out;   // f32: ys[8192*32] then pc

    char* ws = (char*)d_ws;
    float* WxpT = (float*)ws;                                    //  32 KB
    float* cvec = (float*)(ws + 32768);                          //   1 KB
    float* cumA = (float*)(ws + 33792);                          //  32 KB
    float* UAcc = (float*)(ws + 66560);                          //   8 MB f32
    // total ws use: 8.45 MB (acc_s aliases UAcc in place)

    k_prep<<<H_, 64, 0, stream>>>(Wx, Wp, bp, b, WxpT, cvec);
    k_u<<<T_ / 8, 256, 0, stream>>>(x, WxpT, cvec, UAcc);
    act_chain<<<1, 256, 0, stream>>>(Ws, Wx, wh, bh, h0, UAcc, cumA,
                                     out + (size_t)T_ * IO_);
    k_out<<<T_ / 8, 256, 0, stream>>>(UAcc, Wo, bo, cumA, out);
}